// Round 7
// baseline (120.242 us; speedup 1.0000x reference)
//
#include <hip/hip_runtime.h>

#define T_SEQ 512
#define CDIM  1024
#define NH    16
#define DH    64
#define BB    2
#define KD    8

#define BETA_LOG2E 46.16624131f   // 32*log2(e)
#define LOG2E      1.4426950408889634f

typedef unsigned short u16;
typedef __attribute__((ext_vector_type(8))) short bf16x8;
typedef __attribute__((ext_vector_type(4))) float f32x4;

__device__ inline u16 f2bf(float f) {
    unsigned int u = __builtin_bit_cast(unsigned int, f);
    unsigned int r = (u + 0x7fffu + ((u >> 16) & 1u)) >> 16;
    return (u16)r;
}
__device__ inline float bf2f(u16 v) {
    unsigned int u = ((unsigned int)v) << 16;
    return __builtin_bit_cast(float, u);
}

__device__ inline void gload_lds16(const void* g, void* l) {
    __builtin_amdgcn_global_load_lds(
        (const __attribute__((address_space(1))) void*)g,
        (__attribute__((address_space(3))) void*)l, 16, 0, 0);
}

// ---------------------------------------------------------------------------
// Prep: z=0..3 -> transpose W to bf16 [N][K]; z=4 -> convert x to bf16.
// Block (0,0,4) also zeroes the attention completion counters.
// ---------------------------------------------------------------------------
__global__ __launch_bounds__(256)
void prep_kernel(const float* __restrict__ x,
                 const float* __restrict__ W0, const float* __restrict__ W1,
                 const float* __restrict__ W2, const float* __restrict__ W3,
                 u16* __restrict__ xb,
                 u16* __restrict__ T0, u16* __restrict__ T1,
                 u16* __restrict__ T2, u16* __restrict__ T3,
                 int* __restrict__ cnt)
{
    const int tid = threadIdx.x;
    if (blockIdx.z == 4) {
        if (blockIdx.x == 0 && blockIdx.y == 0) cnt[tid] = 0;  // 256 counters
        const int row = blockIdx.y * 32 + (tid >> 3);
        const int col = blockIdx.x * 32 + (tid & 7) * 4;
        float4 v = *(const float4*)&x[(size_t)row * CDIM + col];
        ushort4 o = { f2bf(v.x), f2bf(v.y), f2bf(v.z), f2bf(v.w) };
        *(ushort4*)&xb[(size_t)row * CDIM + col] = o;
        return;
    }
    __shared__ u16 tile[32][33];
    const float* W = (blockIdx.z == 0) ? W0 : (blockIdx.z == 1) ? W1
                   : (blockIdx.z == 2) ? W2 : W3;
    u16* Tt        = (blockIdx.z == 0) ? T0 : (blockIdx.z == 1) ? T1
                   : (blockIdx.z == 2) ? T2 : T3;
    const int k0 = blockIdx.y * 32, n0 = blockIdx.x * 32;
    const int r = tid >> 3, c4 = (tid & 7) * 4;

    float4 v = *(const float4*)&W[(size_t)(k0 + r) * CDIM + n0 + c4];
    tile[r][c4 + 0] = f2bf(v.x);
    tile[r][c4 + 1] = f2bf(v.y);
    tile[r][c4 + 2] = f2bf(v.z);
    tile[r][c4 + 3] = f2bf(v.w);
    __syncthreads();
    ushort4 o;
    o.x = tile[c4 + 0][r];
    o.y = tile[c4 + 1][r];
    o.z = tile[c4 + 2][r];
    o.w = tile[c4 + 3][r];
    *(ushort4*)&Tt[(size_t)(n0 + r) * CDIM + k0 + c4] = o;
}

// ---------------------------------------------------------------------------
// Fused QKV GEMM. 64x64 tile, BK=64, DOUBLE-BUFFERED LDS with counted
// vmcnt(4) (loads stay in flight across raw s_barriers). XCD-swizzled grid.
// z=0/1: epilogue RoPE + RMS-norm + digit projection. z=2: V^T bf16 out.
// ---------------------------------------------------------------------------
__global__ __launch_bounds__(256)
void gemm_qkv_fused(const u16* __restrict__ A,
                    const u16* __restrict__ Bq, const u16* __restrict__ Bk,
                    const u16* __restrict__ Bv,
                    const float* __restrict__ cosp, const float* __restrict__ sinp,
                    const float* __restrict__ Wdq, const float* __restrict__ Wdk,
                    float* __restrict__ qdig, float* __restrict__ kdig,
                    u16* __restrict__ Vt)
{
    // [0,8K)=As0 [8K,16K)=As1 [16K,24K)=Bs0 [24K,32K)=Bs1 bytes; Cf aliases.
    __shared__ __align__(16) char smem[32768];
    u16* As = (u16*)smem;            // + buf*4096 (u16 units)
    u16* Bs = As + 8192;             // + buf*4096
    float* Cf = (float*)smem;        // [64][65] after MFMA phase

    // XCD swizzle: 768 blocks -> 96 consecutive per XCD
    const int wg = (blockIdx.x & 7) * 96 + (blockIdx.x >> 3);
    const int z = wg >> 8;
    const int rem = wg & 255;
    const int h = rem & 15;
    const int m0 = (rem >> 4) * 64;
    const int n0 = h * 64;

    const u16* Bt = (z == 0) ? Bq : (z == 1) ? Bk : Bv;

    const int tid = threadIdx.x;
    const int l = tid & 63, w = tid >> 6;
    const int wr = (w >> 1) * 32, wc = (w & 1) * 32;
    const int srow = l >> 3;
    const int sslot = (l & 7) ^ srow;

    f32x4 acc[2][2];
    #pragma unroll
    for (int i = 0; i < 2; ++i)
        #pragma unroll
        for (int j = 0; j < 2; ++j)
            acc[i][j] = (f32x4){0.f, 0.f, 0.f, 0.f};

    auto STAGE = [&](int buf, int k0) {
        #pragma unroll
        for (int q = 0; q < 2; ++q) {
            const int row = w * 16 + q * 8 + srow;
            gload_lds16(A  + (size_t)(m0 + row) * CDIM + k0 + sslot * 8,
                        &As[buf * 4096 + (w * 16 + q * 8) * 64]);
            gload_lds16(Bt + (size_t)(n0 + row) * CDIM + k0 + sslot * 8,
                        &Bs[buf * 4096 + (w * 16 + q * 8) * 64]);
        }
    };

    STAGE(0, 0);
    for (int t = 0; t < 16; ++t) {
        const int cur = t & 1;
        if (t < 15) {
            STAGE(cur ^ 1, (t + 1) * 64);
            asm volatile("s_waitcnt vmcnt(4)" ::: "memory");
        } else {
            asm volatile("s_waitcnt vmcnt(0)" ::: "memory");
        }
        __builtin_amdgcn_sched_barrier(0);
        __builtin_amdgcn_s_barrier();

        const u16* Ab = &As[cur * 4096];
        const u16* Bb = &Bs[cur * 4096];
        bf16x8 af[2][2], bfr[2][2];
        #pragma unroll
        for (int i = 0; i < 2; ++i)
            #pragma unroll
            for (int kh = 0; kh < 2; ++kh) {
                const int ra = wr + i * 16 + (l & 15);
                const int sa = (kh * 4 + (l >> 4)) ^ (ra & 7);
                af[i][kh] = *(const bf16x8*)&Ab[ra * 64 + sa * 8];
                const int rb = wc + i * 16 + (l & 15);
                const int sb = (kh * 4 + (l >> 4)) ^ (rb & 7);
                bfr[i][kh] = *(const bf16x8*)&Bb[rb * 64 + sb * 8];
            }
        #pragma unroll
        for (int kh = 0; kh < 2; ++kh)
            #pragma unroll
            for (int i = 0; i < 2; ++i)
                #pragma unroll
                for (int j = 0; j < 2; ++j)
                    acc[i][j] = __builtin_amdgcn_mfma_f32_16x16x32_bf16(
                        af[i][kh], bfr[j][kh], acc[i][j], 0, 0, 0);
        __builtin_amdgcn_s_barrier();
    }
    __syncthreads();   // staging fully done; smem becomes Cf

    if (z == 2) {
        #pragma unroll
        for (int i = 0; i < 2; ++i)
            #pragma unroll
            for (int j = 0; j < 2; ++j) {
                const int mm = wr + i * 16 + (l >> 4) * 4;
                const int dd = wc + j * 16 + (l & 15);
                #pragma unroll
                for (int r = 0; r < 4; ++r)
                    Cf[dd * 65 + mm + r] = acc[i][j][r];
            }
        __syncthreads();
        const int b = m0 >> 9, t0 = m0 & (T_SEQ - 1);
        u16* vbase = Vt + ((size_t)(b * NH + h) * 64) * T_SEQ;
        #pragma unroll
        for (int it = 0; it < 16; ++it) {
            const int d = it * 4 + w;
            vbase[(size_t)d * T_SEQ + t0 + l] = f2bf(Cf[d * 65 + l]);
        }
        return;
    }

    // Q/K path: Cf[m][d], stride 65
    #pragma unroll
    for (int i = 0; i < 2; ++i)
        #pragma unroll
        for (int j = 0; j < 2; ++j) {
            const int mm = wr + i * 16 + (l >> 4) * 4;
            const int dd = wc + j * 16 + (l & 15);
            #pragma unroll
            for (int r = 0; r < 4; ++r)
                Cf[(mm + r) * 65 + dd] = acc[i][j][r];
        }

    const float* Wd = z ? Wdk : Wdq;
    float* dig = z ? kdig : qdig;

    const int dl = l & 15, rq = l >> 4;
    float wreg[4][8];   // Wd rows dl, dl+16, dl+32, dl+48
    #pragma unroll
    for (int d4 = 0; d4 < 4; ++d4) {
        *(float4*)&wreg[d4][0] = *(const float4*)&Wd[(dl + d4 * 16) * 8];
        *(float4*)&wreg[d4][4] = *(const float4*)&Wd[(dl + d4 * 16) * 8 + 4];
    }
    __syncthreads();

    for (int g = 0; g < 4; ++g) {
        const int m = w * 16 + g * 4 + rq;
        const int mg = m0 + m;
        const int b = mg >> 9, t = mg & (T_SEQ - 1);

        const float* cr = &Cf[m * 65];
        float r0 = cr[dl], r1 = cr[dl + 16], r2 = cr[dl + 32], r3 = cr[dl + 48];
        float c0 = cosp[t * 32 + dl], c1 = cosp[t * 32 + dl + 16];
        float s0 = sinp[t * 32 + dl], s1 = sinp[t * 32 + dl + 16];
        float v0 = r0 * c0 - r2 * s0;
        float v1 = r1 * c1 - r3 * s1;
        float v2 = r0 * s0 + r2 * c0;
        float v3 = r1 * s1 + r3 * c1;

        float ss = v0 * v0 + v1 * v1 + v2 * v2 + v3 * v3;
        #pragma unroll
        for (int off = 1; off < 16; off <<= 1) ss += __shfl_xor(ss, off);
        float sc = rsqrtf(ss * (1.0f / 64.0f) + 1e-6f);
        v0 *= sc; v1 *= sc; v2 *= sc; v3 *= sc;

        float zz[8];
        #pragma unroll
        for (int j = 0; j < 8; ++j)
            zz[j] = v0 * wreg[0][j] + v1 * wreg[1][j] + v2 * wreg[2][j] + v3 * wreg[3][j];
        #pragma unroll
        for (int j = 0; j < 8; ++j) {
            #pragma unroll
            for (int off = 1; off < 16; off <<= 1) zz[j] += __shfl_xor(zz[j], off);
        }
        float zsel = zz[0];
        #pragma unroll
        for (int j = 1; j < 8; ++j) zsel = (dl == j) ? zz[j] : zsel;
        if (dl < 8)
            dig[((size_t)(b * NH + h) * T_SEQ + t) * KD + dl] =
                1.0f / (1.0f + exp2f(-LOG2E * zsel));
    }
}

// ---------------------------------------------------------------------------
// Ultrametric attention partial (MFMA) + FOLDED COMBINE.
// One 64q x 64k tile per block; the last block to finish a (bh,c) q-chunk
// (completion counter) re-reads the partials, normalizes, writes y bf16.
// ---------------------------------------------------------------------------
__global__ __launch_bounds__(256)
void attn_partial(const float* __restrict__ qdig, const float* __restrict__ kdig,
                  const u16* __restrict__ Vt,
                  u16* __restrict__ pacc, float* __restrict__ pdeng,
                  int* __restrict__ cnt, u16* __restrict__ y)
{
    __shared__ u16 Vs[4096];    // [d][k] swizzled, 8KB
    __shared__ u16 Ps[4096];    // [q][k] swizzled, 8KB
    __shared__ float qds[512];  // [q][8]
    __shared__ int winflag;

    const int tid = threadIdx.x;
    const int w = tid >> 6, l = tid & 63;

    // XCD swizzle: 1152 blocks -> 144 consecutive per XCD
    const int wg = (blockIdx.x & 7) * 144 + (blockIdx.x >> 3);
    const int tile = wg % 36;
    const int bh = wg / 36;
    const size_t bhT = (size_t)bh * T_SEQ;

    int id = tile, c = 0;
    while (id >= c + 1) { id -= (c + 1); ++c; }
    const int kt = id;
    const int k0 = kt * 64;

    const int srow = l >> 3, sslot = (l & 7) ^ srow;
    #pragma unroll
    for (int q2 = 0; q2 < 2; ++q2) {
        const int R0 = w * 16 + q2 * 8;
        gload_lds16(Vt + ((size_t)bh * 64 + R0 + srow) * T_SEQ + k0 + sslot * 8,
                    &Vs[R0 * 64]);
    }
    *(float2*)&qds[tid * 2] = *(const float2*)&qdig[(bhT + c * 64) * KD + tid * 2];

    float kd[8];
    {
        const float* kp = &kdig[(bhT + k0 + l) * KD];
        *(float4*)&kd[0] = *(const float4*)kp;
        *(float4*)&kd[4] = *(const float4*)(kp + 4);
    }
    __syncthreads();

    const bool diag = (kt == c);
    for (int qi = 0; qi < 16; ++qi) {
        const int qrow = w * 16 + qi;
        float qd[8];
        *(float4*)&qd[0] = *(const float4*)&qds[qrow * 8];
        *(float4*)&qd[4] = *(const float4*)&qds[qrow * 8 + 4];
        float S = 0.f, lcp = 0.f;
        #pragma unroll
        for (int jj = 0; jj < 8; ++jj) {
            float d = qd[jj] - kd[jj];
            S += d * d;
            lcp += exp2f(-BETA_LOG2E * S);
        }
        float wgt = exp2f(lcp);
        if (diag && l > qrow) wgt = 0.f;
        Ps[qrow * 64 + (((l >> 3) ^ (qi & 7)) << 3) + (l & 7)] = f2bf(wgt);
    }
    __syncthreads();

    const int wr = (w >> 1) * 32, wc = (w & 1) * 32;
    f32x4 acc[2][2], accd[2];
    #pragma unroll
    for (int i = 0; i < 2; ++i) {
        accd[i] = (f32x4){0.f, 0.f, 0.f, 0.f};
        #pragma unroll
        for (int j = 0; j < 2; ++j) acc[i][j] = (f32x4){0.f, 0.f, 0.f, 0.f};
    }
    bf16x8 ones;
    #pragma unroll
    for (int i = 0; i < 8; ++i) ones[i] = (short)0x3F80;

    #pragma unroll
    for (int kh = 0; kh < 2; ++kh) {
        bf16x8 af[2], bfr[2];
        #pragma unroll
        for (int i = 0; i < 2; ++i) {
            const int ra = wr + i * 16 + (l & 15);
            const int sa = (kh * 4 + (l >> 4)) ^ (ra & 7);
            af[i] = *(const bf16x8*)&Ps[ra * 64 + sa * 8];
            const int rb = wc + i * 16 + (l & 15);
            const int sb = (kh * 4 + (l >> 4)) ^ (rb & 7);
            bfr[i] = *(const bf16x8*)&Vs[rb * 64 + sb * 8];
        }
        #pragma unroll
        for (int i = 0; i < 2; ++i) {
            accd[i] = __builtin_amdgcn_mfma_f32_16x16x32_bf16(af[i], ones, accd[i], 0, 0, 0);
            #pragma unroll
            for (int j = 0; j < 2; ++j)
                acc[i][j] = __builtin_amdgcn_mfma_f32_16x16x32_bf16(
                    af[i], bfr[j], acc[i][j], 0, 0, 0);
        }
    }

    const int task = bh * 36 + tile;
    u16* pa = pacc + (size_t)task * 4096;
    #pragma unroll
    for (int i = 0; i < 2; ++i) {
        const int row = wr + i * 16 + (l >> 4) * 4;
        #pragma unroll
        for (int j = 0; j < 2; ++j) {
            const int col = wc + j * 16 + (l & 15);
            #pragma unroll
            for (int r = 0; r < 4; ++r)
                pa[(size_t)(row + r) * 64 + col] = f2bf(acc[i][j][r]);
        }
        if ((l & 15) == 0) {
            #pragma unroll
            for (int r = 0; r < 4; ++r)
                pdeng[(size_t)task * 64 + row + r] = accd[i][r];
        }
    }

    // ---- folded combine: last block of this (bh, c) chunk does it ----
    __syncthreads();                 // all partial stores drained (vmcnt 0)
    if (tid == 0) {
        __threadfence();             // release: make pacc/pdeng visible
        int old = atomicAdd(&cnt[bh * 8 + c], 1);
        winflag = (old == c) ? 1 : 0;
    }
    __syncthreads();
    if (!winflag) return;
    __threadfence();                 // acquire: invalidate stale cache lines

    const int r = tid >> 2, cg = (tid & 3) * 16;
    const int base = bh * 36 + c * (c + 1) / 2;
    float accf[16] = {};
    float den = 0.f;
    for (int k2 = 0; k2 <= c; ++k2) {
        const u16* ps = pacc + (size_t)(base + k2) * 4096 + r * 64 + cg;
        ushort4 v0 = *(const ushort4*)(ps + 0);
        ushort4 v1 = *(const ushort4*)(ps + 4);
        ushort4 v2 = *(const ushort4*)(ps + 8);
        ushort4 v3 = *(const ushort4*)(ps + 12);
        accf[0]  += bf2f(v0.x); accf[1]  += bf2f(v0.y);
        accf[2]  += bf2f(v0.z); accf[3]  += bf2f(v0.w);
        accf[4]  += bf2f(v1.x); accf[5]  += bf2f(v1.y);
        accf[6]  += bf2f(v1.z); accf[7]  += bf2f(v1.w);
        accf[8]  += bf2f(v2.x); accf[9]  += bf2f(v2.y);
        accf[10] += bf2f(v2.z); accf[11] += bf2f(v2.w);
        accf[12] += bf2f(v3.x); accf[13] += bf2f(v3.y);
        accf[14] += bf2f(v3.z); accf[15] += bf2f(v3.w);
        den += pdeng[(size_t)(base + k2) * 64 + r];
    }
    float inv = 1.f / fmaxf(den, 1e-9f);

    const int b = bh >> 4, h = bh & 15;
    u16* yr = y + ((size_t)(b * T_SEQ + c * 64 + r)) * CDIM + h * DH + cg;
    uint4 p0, p1;
    p0.x = f2bf(accf[0] * inv)  | ((unsigned)f2bf(accf[1] * inv)  << 16);
    p0.y = f2bf(accf[2] * inv)  | ((unsigned)f2bf(accf[3] * inv)  << 16);
    p0.z = f2bf(accf[4] * inv)  | ((unsigned)f2bf(accf[5] * inv)  << 16);
    p0.w = f2bf(accf[6] * inv)  | ((unsigned)f2bf(accf[7] * inv)  << 16);
    p1.x = f2bf(accf[8] * inv)  | ((unsigned)f2bf(accf[9] * inv)  << 16);
    p1.y = f2bf(accf[10] * inv) | ((unsigned)f2bf(accf[11] * inv) << 16);
    p1.z = f2bf(accf[12] * inv) | ((unsigned)f2bf(accf[13] * inv) << 16);
    p1.w = f2bf(accf[14] * inv) | ((unsigned)f2bf(accf[15] * inv) << 16);
    *(uint4*)(yr + 0) = p0;
    *(uint4*)(yr + 8) = p1;
}

// ---------------------------------------------------------------------------
// Output projection GEMM, 32x64 tiles, BK=64, double-buffered with counted
// vmcnt(3). XCD-swizzled 512-block grid.
// ---------------------------------------------------------------------------
__global__ __launch_bounds__(256)
void gemm_proj(const u16* __restrict__ A, const u16* __restrict__ Bt,
               float* __restrict__ C)
{
    // u16 units: As0@0 As1@2048 Bs0@4096 Bs1@8192  (24KB total)
    __shared__ __align__(16) u16 S[12288];

    const int wg = (blockIdx.x & 7) * 64 + (blockIdx.x >> 3);
    const int n0 = (wg & 15) * 64;
    const int m0 = (wg >> 4) * 32;

    const int tid = threadIdx.x;
    const int l = tid & 63, w = tid >> 6;
    const int wr = (w & 1) * 16, wc = (w >> 1) * 32;
    const int srow = l >> 3;
    const int sslot = (l & 7) ^ srow;

    f32x4 acc[2];
    acc[0] = (f32x4){0.f, 0.f, 0.f, 0.f};
    acc[1] = (f32x4){0.f, 0.f, 0.f, 0.f};

    auto STAGE = [&](int buf, int k0) {
        const int rowa = w * 8 + srow;
        gload_lds16(A + (size_t)(m0 + rowa) * CDIM + k0 + sslot * 8,
                    &S[buf * 2048 + (w * 8) * 64]);
        #pragma unroll
        for (int q = 0; q < 2; ++q) {
            const int row = w * 16 + q * 8 + srow;
            gload_lds16(Bt + (size_t)(n0 + row) * CDIM + k0 + sslot * 8,
                        &S[4096 + buf * 4096 + (w * 16 + q * 8) * 64]);
        }
    };

    STAGE(0, 0);
    for (int t = 0; t < 16; ++t) {
        const int cur = t & 1;
        if (t < 15) {
            STAGE(cur ^ 1, (t + 1) * 64);
            asm volatile("s_waitcnt vmcnt(3)" ::: "memory");
        } else {
            asm volatile("s_waitcnt vmcnt(0)" ::: "memory");
        }
        __builtin_amdgcn_sched_barrier(0);
        __builtin_amdgcn_s_barrier();

        const u16* Ab = &S[cur * 2048];
        const u16* Bb = &S[4096 + cur * 4096];
        #pragma unroll
        for (int kh = 0; kh < 2; ++kh) {
            const int ra = wr + (l & 15);
            const int sa = (kh * 4 + (l >> 4)) ^ (ra & 7);
            bf16x8 af = *(const bf16x8*)&Ab[ra * 64 + sa * 8];
            #pragma unroll
            for (int j = 0; j < 2; ++j) {
                const int rb = wc + j * 16 + (l & 15);
                const int sb = (kh * 4 + (l >> 4)) ^ (rb & 7);
                bf16x8 bfr = *(const bf16x8*)&Bb[rb * 64 + sb * 8];
                acc[j] = __builtin_amdgcn_mfma_f32_16x16x32_bf16(
                    af, bfr, acc[j], 0, 0, 0);
            }
        }
        __builtin_amdgcn_s_barrier();
    }

    #pragma unroll
    for (int j = 0; j < 2; ++j) {
        const int row = m0 + wr + (l >> 4) * 4;
        const int col = n0 + wc + j * 16 + (l & 15);
        #pragma unroll
        for (int r = 0; r < 4; ++r)
            C[(size_t)(row + r) * CDIM + col] = acc[j][r];
    }
}

// ---------------------------------------------------------------------------
extern "C" void kernel_launch(void* const* d_in, const int* in_sizes, int n_in,
                              void* d_out, int out_size, void* d_ws, size_t ws_size,
                              hipStream_t stream)
{
    (void)in_sizes; (void)n_in; (void)out_size; (void)ws_size;
    const float* x    = (const float*)d_in[0];
    const float* cosp = (const float*)d_in[1];
    const float* sinp = (const float*)d_in[2];
    const float* Wq   = (const float*)d_in[3];
    const float* Wk   = (const float*)d_in[4];
    const float* Wv   = (const float*)d_in[5];
    const float* Wo   = (const float*)d_in[6];
    const float* Wdq  = (const float*)d_in[7];
    const float* Wdk  = (const float*)d_in[8];
    float* out = (float*)d_out;

    const int M = BB * T_SEQ;                 // 1024
    const size_t MC = (size_t)M * CDIM;       // 1M elems
    char* p = (char*)d_ws;
    float* qdig = (float*)p; p += (size_t)M * NH * KD * 4;   // 512KB
    float* kdig = (float*)p; p += (size_t)M * NH * KD * 4;   // 512KB
    u16* xb   = (u16*)p; p += MC * 2;
    u16* wqt  = (u16*)p; p += MC * 2;
    u16* wkt  = (u16*)p; p += MC * 2;
    u16* wvt  = (u16*)p; p += MC * 2;
    u16* wot  = (u16*)p; p += MC * 2;
    u16* Vt   = (u16*)p; p += MC * 2;         // [b][h][d][t] bf16, 2MB
    u16* ybuf = (u16*)p; p += MC * 2;
    u16* pacc = (u16*)p; p += (size_t)1152 * 4096 * 2;       // 9.4MB bf16
    float* pdeng = (float*)p; p += (size_t)1152 * 64 * 4;
    int* cnt = (int*)p; p += 256 * 4;

    dim3 blk(256);
    prep_kernel<<<dim3(32, 32, 5), blk, 0, stream>>>(
        x, Wq, Wk, Wv, Wo, xb, wqt, wkt, wvt, wot, cnt);
    gemm_qkv_fused<<<dim3(768), blk, 0, stream>>>(
        xb, wqt, wkt, wvt, cosp, sinp, Wdq, Wdk, qdig, kdig, Vt);
    attn_partial<<<dim3(1152), blk, 0, stream>>>(
        qdig, kdig, Vt, pacc, pdeng, cnt, ybuf);
    gemm_proj<<<dim3(512), blk, 0, stream>>>(ybuf, wot, out);
}

// Round 9
// 58.095 us; speedup vs baseline: 2.0698x; 2.0698x over previous
//
#include <hip/hip_runtime.h>

#define T_SEQ 512
#define CDIM  1024
#define NH    16
#define DH    64
#define BB    2
#define KD    8

#define BETA_LOG2E 46.16624131f   // 32*log2(e)
#define LOG2E      1.4426950408889634f

typedef unsigned short u16;
typedef __attribute__((ext_vector_type(8))) short bf16x8;
typedef __attribute__((ext_vector_type(4))) float f32x4;

__device__ inline u16 f2bf(float f) {
    unsigned int u = __builtin_bit_cast(unsigned int, f);
    unsigned int r = (u + 0x7fffu + ((u >> 16) & 1u)) >> 16;
    return (u16)r;
}
__device__ inline float bf2f(u16 v) {
    unsigned int u = ((unsigned int)v) << 16;
    return __builtin_bit_cast(float, u);
}

__device__ inline void gload_lds16(const void* g, void* l) {
    __builtin_amdgcn_global_load_lds(
        (const __attribute__((address_space(1))) void*)g,
        (__attribute__((address_space(3))) void*)l, 16, 0, 0);
}

// Fused fence+barrier: waitcnt and s_barrier in ONE asm with memory clobber
// so the compiler cannot separate them or move memory ops across (m152/rule-18
// hardening of the counted-vmcnt pipeline).
#define PIPE_BAR_VM4()  do { asm volatile("s_waitcnt vmcnt(4)\n\ts_barrier" ::: "memory"); __builtin_amdgcn_sched_barrier(0); } while (0)
#define PIPE_BAR_VM3()  do { asm volatile("s_waitcnt vmcnt(3)\n\ts_barrier" ::: "memory"); __builtin_amdgcn_sched_barrier(0); } while (0)
#define PIPE_BAR_VM0()  do { asm volatile("s_waitcnt vmcnt(0)\n\ts_barrier" ::: "memory"); __builtin_amdgcn_sched_barrier(0); } while (0)
#define PIPE_BAR_END()  do { asm volatile("s_waitcnt lgkmcnt(0)\n\ts_barrier" ::: "memory"); __builtin_amdgcn_sched_barrier(0); } while (0)

// ---------------------------------------------------------------------------
// Prep: z=0..3 -> transpose W to bf16 [N][K]; z=4 -> convert x to bf16.
// ---------------------------------------------------------------------------
__global__ __launch_bounds__(256)
void prep_kernel(const float* __restrict__ x,
                 const float* __restrict__ W0, const float* __restrict__ W1,
                 const float* __restrict__ W2, const float* __restrict__ W3,
                 u16* __restrict__ xb,
                 u16* __restrict__ T0, u16* __restrict__ T1,
                 u16* __restrict__ T2, u16* __restrict__ T3)
{
    const int tid = threadIdx.x;
    if (blockIdx.z == 4) {
        const int row = blockIdx.y * 32 + (tid >> 3);
        const int col = blockIdx.x * 32 + (tid & 7) * 4;
        float4 v = *(const float4*)&x[(size_t)row * CDIM + col];
        ushort4 o = { f2bf(v.x), f2bf(v.y), f2bf(v.z), f2bf(v.w) };
        *(ushort4*)&xb[(size_t)row * CDIM + col] = o;
        return;
    }
    __shared__ u16 tile[32][33];
    const float* W = (blockIdx.z == 0) ? W0 : (blockIdx.z == 1) ? W1
                   : (blockIdx.z == 2) ? W2 : W3;
    u16* Tt        = (blockIdx.z == 0) ? T0 : (blockIdx.z == 1) ? T1
                   : (blockIdx.z == 2) ? T2 : T3;
    const int k0 = blockIdx.y * 32, n0 = blockIdx.x * 32;
    const int r = tid >> 3, c4 = (tid & 7) * 4;

    float4 v = *(const float4*)&W[(size_t)(k0 + r) * CDIM + n0 + c4];
    tile[r][c4 + 0] = f2bf(v.x);
    tile[r][c4 + 1] = f2bf(v.y);
    tile[r][c4 + 2] = f2bf(v.z);
    tile[r][c4 + 3] = f2bf(v.w);
    __syncthreads();
    ushort4 o;
    o.x = tile[c4 + 0][r];
    o.y = tile[c4 + 1][r];
    o.z = tile[c4 + 2][r];
    o.w = tile[c4 + 3][r];
    *(ushort4*)&Tt[(size_t)(n0 + r) * CDIM + k0 + c4] = o;
}

// ---------------------------------------------------------------------------
// Fused QKV GEMM. 64x64 tile, BK=64, double-buffered LDS, counted vmcnt(4)
// with FUSED waitcnt+barrier asm (race-hardened). XCD-swizzled grid.
// z=0/1: epilogue RoPE + RMS-norm + digit projection. z=2: V^T bf16 out.
// ---------------------------------------------------------------------------
__global__ __launch_bounds__(256)
void gemm_qkv_fused(const u16* __restrict__ A,
                    const u16* __restrict__ Bq, const u16* __restrict__ Bk,
                    const u16* __restrict__ Bv,
                    const float* __restrict__ cosp, const float* __restrict__ sinp,
                    const float* __restrict__ Wdq, const float* __restrict__ Wdk,
                    float* __restrict__ qdig, float* __restrict__ kdig,
                    u16* __restrict__ Vt)
{
    // [0,8K)=As0 [8K,16K)=As1 [16K,24K)=Bs0 [24K,32K)=Bs1 bytes; Cf aliases.
    __shared__ __align__(16) char smem[32768];
    u16* As = (u16*)smem;            // + buf*4096 (u16 units)
    u16* Bs = As + 8192;             // + buf*4096
    float* Cf = (float*)smem;        // [64][65] after MFMA phase

    // XCD swizzle: 768 blocks -> 96 consecutive per XCD
    const int wg = (blockIdx.x & 7) * 96 + (blockIdx.x >> 3);
    const int z = wg >> 8;
    const int rem = wg & 255;
    const int h = rem & 15;
    const int m0 = (rem >> 4) * 64;
    const int n0 = h * 64;

    const u16* Bt = (z == 0) ? Bq : (z == 1) ? Bk : Bv;

    const int tid = threadIdx.x;
    const int l = tid & 63, w = tid >> 6;
    const int wr = (w >> 1) * 32, wc = (w & 1) * 32;
    const int srow = l >> 3;
    const int sslot = (l & 7) ^ srow;

    f32x4 acc[2][2];
    #pragma unroll
    for (int i = 0; i < 2; ++i)
        #pragma unroll
        for (int j = 0; j < 2; ++j)
            acc[i][j] = (f32x4){0.f, 0.f, 0.f, 0.f};

    auto STAGE = [&](int buf, int k0) {
        #pragma unroll
        for (int q = 0; q < 2; ++q) {
            const int row = w * 16 + q * 8 + srow;
            gload_lds16(A  + (size_t)(m0 + row) * CDIM + k0 + sslot * 8,
                        &As[buf * 4096 + (w * 16 + q * 8) * 64]);
            gload_lds16(Bt + (size_t)(n0 + row) * CDIM + k0 + sslot * 8,
                        &Bs[buf * 4096 + (w * 16 + q * 8) * 64]);
        }
    };

    STAGE(0, 0);
    for (int t = 0; t < 16; ++t) {
        const int cur = t & 1;
        if (t < 15) {
            STAGE(cur ^ 1, (t + 1) * 64);
            PIPE_BAR_VM4();
        } else {
            PIPE_BAR_VM0();
        }

        const u16* Ab = &As[cur * 4096];
        const u16* Bb = &Bs[cur * 4096];
        bf16x8 af[2][2], bfr[2][2];
        #pragma unroll
        for (int i = 0; i < 2; ++i)
            #pragma unroll
            for (int kh = 0; kh < 2; ++kh) {
                const int ra = wr + i * 16 + (l & 15);
                const int sa = (kh * 4 + (l >> 4)) ^ (ra & 7);
                af[i][kh] = *(const bf16x8*)&Ab[ra * 64 + sa * 8];
                const int rb = wc + i * 16 + (l & 15);
                const int sb = (kh * 4 + (l >> 4)) ^ (rb & 7);
                bfr[i][kh] = *(const bf16x8*)&Bb[rb * 64 + sb * 8];
            }
        #pragma unroll
        for (int kh = 0; kh < 2; ++kh)
            #pragma unroll
            for (int i = 0; i < 2; ++i)
                #pragma unroll
                for (int j = 0; j < 2; ++j)
                    acc[i][j] = __builtin_amdgcn_mfma_f32_16x16x32_bf16(
                        af[i][kh], bfr[j][kh], acc[i][j], 0, 0, 0);
        PIPE_BAR_END();
    }
    __syncthreads();   // full drain; smem becomes Cf

    if (z == 2) {
        #pragma unroll
        for (int i = 0; i < 2; ++i)
            #pragma unroll
            for (int j = 0; j < 2; ++j) {
                const int mm = wr + i * 16 + (l >> 4) * 4;
                const int dd = wc + j * 16 + (l & 15);
                #pragma unroll
                for (int r = 0; r < 4; ++r)
                    Cf[dd * 65 + mm + r] = acc[i][j][r];
            }
        __syncthreads();
        const int b = m0 >> 9, t0 = m0 & (T_SEQ - 1);
        u16* vbase = Vt + ((size_t)(b * NH + h) * 64) * T_SEQ;
        #pragma unroll
        for (int it = 0; it < 16; ++it) {
            const int d = it * 4 + w;
            vbase[(size_t)d * T_SEQ + t0 + l] = f2bf(Cf[d * 65 + l]);
        }
        return;
    }

    // Q/K path: Cf[m][d], stride 65
    #pragma unroll
    for (int i = 0; i < 2; ++i)
        #pragma unroll
        for (int j = 0; j < 2; ++j) {
            const int mm = wr + i * 16 + (l >> 4) * 4;
            const int dd = wc + j * 16 + (l & 15);
            #pragma unroll
            for (int r = 0; r < 4; ++r)
                Cf[(mm + r) * 65 + dd] = acc[i][j][r];
        }

    const float* Wd = z ? Wdk : Wdq;
    float* dig = z ? kdig : qdig;

    const int dl = l & 15, rq = l >> 4;
    float wreg[4][8];   // Wd rows dl, dl+16, dl+32, dl+48
    #pragma unroll
    for (int d4 = 0; d4 < 4; ++d4) {
        *(float4*)&wreg[d4][0] = *(const float4*)&Wd[(dl + d4 * 16) * 8];
        *(float4*)&wreg[d4][4] = *(const float4*)&Wd[(dl + d4 * 16) * 8 + 4];
    }
    __syncthreads();

    for (int g = 0; g < 4; ++g) {
        const int m = w * 16 + g * 4 + rq;
        const int mg = m0 + m;
        const int b = mg >> 9, t = mg & (T_SEQ - 1);

        const float* cr = &Cf[m * 65];
        float r0 = cr[dl], r1 = cr[dl + 16], r2 = cr[dl + 32], r3 = cr[dl + 48];
        float c0 = cosp[t * 32 + dl], c1 = cosp[t * 32 + dl + 16];
        float s0 = sinp[t * 32 + dl], s1 = sinp[t * 32 + dl + 16];
        float v0 = r0 * c0 - r2 * s0;
        float v1 = r1 * c1 - r3 * s1;
        float v2 = r0 * s0 + r2 * c0;
        float v3 = r1 * s1 + r3 * c1;

        float ss = v0 * v0 + v1 * v1 + v2 * v2 + v3 * v3;
        #pragma unroll
        for (int off = 1; off < 16; off <<= 1) ss += __shfl_xor(ss, off);
        float sc = rsqrtf(ss * (1.0f / 64.0f) + 1e-6f);
        v0 *= sc; v1 *= sc; v2 *= sc; v3 *= sc;

        float zz[8];
        #pragma unroll
        for (int j = 0; j < 8; ++j)
            zz[j] = v0 * wreg[0][j] + v1 * wreg[1][j] + v2 * wreg[2][j] + v3 * wreg[3][j];
        #pragma unroll
        for (int j = 0; j < 8; ++j) {
            #pragma unroll
            for (int off = 1; off < 16; off <<= 1) zz[j] += __shfl_xor(zz[j], off);
        }
        float zsel = zz[0];
        #pragma unroll
        for (int j = 1; j < 8; ++j) zsel = (dl == j) ? zz[j] : zsel;
        if (dl < 8)
            dig[((size_t)(b * NH + h) * T_SEQ + t) * KD + dl] =
                1.0f / (1.0f + exp2f(-LOG2E * zsel));
    }
}

// ---------------------------------------------------------------------------
// Ultrametric attention partial (MFMA). One 64q x 64k tile per block.
// Flat 1152-block grid with XCD swizzle. Partial PV bf16; denom fp32.
// ---------------------------------------------------------------------------
__global__ __launch_bounds__(256)
void attn_partial(const float* __restrict__ qdig, const float* __restrict__ kdig,
                  const u16* __restrict__ Vt,
                  u16* __restrict__ pacc, float* __restrict__ pdeng)
{
    __shared__ u16 Vs[4096];    // [d][k] swizzled, 8KB
    __shared__ u16 Ps[4096];    // [q][k] swizzled, 8KB
    __shared__ float qds[512];  // [q][8]

    const int tid = threadIdx.x;
    const int w = tid >> 6, l = tid & 63;

    // XCD swizzle: 1152 blocks -> 144 consecutive per XCD
    const int wg = (blockIdx.x & 7) * 144 + (blockIdx.x >> 3);
    const int tile = wg % 36;
    const int bh = wg / 36;
    const size_t bhT = (size_t)bh * T_SEQ;

    int id = tile, c = 0;
    while (id >= c + 1) { id -= (c + 1); ++c; }
    const int kt = id;
    const int k0 = kt * 64;

    const int srow = l >> 3, sslot = (l & 7) ^ srow;
    #pragma unroll
    for (int q2 = 0; q2 < 2; ++q2) {
        const int R0 = w * 16 + q2 * 8;
        gload_lds16(Vt + ((size_t)bh * 64 + R0 + srow) * T_SEQ + k0 + sslot * 8,
                    &Vs[R0 * 64]);
    }
    *(float2*)&qds[tid * 2] = *(const float2*)&qdig[(bhT + c * 64) * KD + tid * 2];

    float kd[8];
    {
        const float* kp = &kdig[(bhT + k0 + l) * KD];
        *(float4*)&kd[0] = *(const float4*)kp;
        *(float4*)&kd[4] = *(const float4*)(kp + 4);
    }
    __syncthreads();

    const bool diag = (kt == c);
    for (int qi = 0; qi < 16; ++qi) {
        const int qrow = w * 16 + qi;
        float qd[8];
        *(float4*)&qd[0] = *(const float4*)&qds[qrow * 8];
        *(float4*)&qd[4] = *(const float4*)&qds[qrow * 8 + 4];
        float S = 0.f, lcp = 0.f;
        #pragma unroll
        for (int jj = 0; jj < 8; ++jj) {
            float d = qd[jj] - kd[jj];
            S += d * d;
            lcp += exp2f(-BETA_LOG2E * S);
        }
        float wgt = exp2f(lcp);
        if (diag && l > qrow) wgt = 0.f;
        Ps[qrow * 64 + (((l >> 3) ^ (qi & 7)) << 3) + (l & 7)] = f2bf(wgt);
    }
    __syncthreads();

    const int wr = (w >> 1) * 32, wc = (w & 1) * 32;
    f32x4 acc[2][2], accd[2];
    #pragma unroll
    for (int i = 0; i < 2; ++i) {
        accd[i] = (f32x4){0.f, 0.f, 0.f, 0.f};
        #pragma unroll
        for (int j = 0; j < 2; ++j) acc[i][j] = (f32x4){0.f, 0.f, 0.f, 0.f};
    }
    bf16x8 ones;
    #pragma unroll
    for (int i = 0; i < 8; ++i) ones[i] = (short)0x3F80;

    #pragma unroll
    for (int kh = 0; kh < 2; ++kh) {
        bf16x8 af[2], bfr[2];
        #pragma unroll
        for (int i = 0; i < 2; ++i) {
            const int ra = wr + i * 16 + (l & 15);
            const int sa = (kh * 4 + (l >> 4)) ^ (ra & 7);
            af[i] = *(const bf16x8*)&Ps[ra * 64 + sa * 8];
            const int rb = wc + i * 16 + (l & 15);
            const int sb = (kh * 4 + (l >> 4)) ^ (rb & 7);
            bfr[i] = *(const bf16x8*)&Vs[rb * 64 + sb * 8];
        }
        #pragma unroll
        for (int i = 0; i < 2; ++i) {
            accd[i] = __builtin_amdgcn_mfma_f32_16x16x32_bf16(af[i], ones, accd[i], 0, 0, 0);
            #pragma unroll
            for (int j = 0; j < 2; ++j)
                acc[i][j] = __builtin_amdgcn_mfma_f32_16x16x32_bf16(
                    af[i], bfr[j], acc[i][j], 0, 0, 0);
        }
    }

    const int task = bh * 36 + tile;
    u16* pa = pacc + (size_t)task * 4096;
    #pragma unroll
    for (int i = 0; i < 2; ++i) {
        const int row = wr + i * 16 + (l >> 4) * 4;
        #pragma unroll
        for (int j = 0; j < 2; ++j) {
            const int col = wc + j * 16 + (l & 15);
            #pragma unroll
            for (int r = 0; r < 4; ++r)
                pa[(size_t)(row + r) * 64 + col] = f2bf(acc[i][j][r]);
        }
        if ((l & 15) == 0) {
            #pragma unroll
            for (int r = 0; r < 4; ++r)
                pdeng[(size_t)task * 64 + row + r] = accd[i][r];
        }
    }
}

// ---------------------------------------------------------------------------
// Combine partials over kt, normalize, write y bf16 (B,T,C).
// Grid (16, NH, BB): x = c*2 + column-half (2 blocks/CU).
// ---------------------------------------------------------------------------
__global__ __launch_bounds__(256)
void attn_combine(const u16* __restrict__ pacc, const float* __restrict__ pdeng,
                  u16* __restrict__ y)
{
    const int c = blockIdx.x >> 1, half = blockIdx.x & 1;
    const int h = blockIdx.y, b = blockIdx.z;
    const int tid = threadIdx.x;
    const int r = tid >> 2, cg = (tid & 3) * 8 + half * 32;
    const int base = (b * NH + h) * 36 + c * (c + 1) / 2;

    float acc[8] = {};
    float den = 0.f;
    for (int kt = 0; kt <= c; ++kt) {
        const u16* pa = pacc + (size_t)(base + kt) * 4096 + r * 64 + cg;
        ushort4 v0 = *(const ushort4*)(pa + 0);
        ushort4 v1 = *(const ushort4*)(pa + 4);
        acc[0] += bf2f(v0.x); acc[1] += bf2f(v0.y);
        acc[2] += bf2f(v0.z); acc[3] += bf2f(v0.w);
        acc[4] += bf2f(v1.x); acc[5] += bf2f(v1.y);
        acc[6] += bf2f(v1.z); acc[7] += bf2f(v1.w);
        den += pdeng[(size_t)(base + kt) * 64 + r];
    }
    float inv = 1.f / fmaxf(den, 1e-9f);

    u16* yr = y + ((size_t)(b * T_SEQ + c * 64 + r)) * CDIM + h * DH + cg;
    uint4 p;
    p.x = f2bf(acc[0] * inv) | ((unsigned)f2bf(acc[1] * inv) << 16);
    p.y = f2bf(acc[2] * inv) | ((unsigned)f2bf(acc[3] * inv) << 16);
    p.z = f2bf(acc[4] * inv) | ((unsigned)f2bf(acc[5] * inv) << 16);
    p.w = f2bf(acc[6] * inv) | ((unsigned)f2bf(acc[7] * inv) << 16);
    *(uint4*)yr = p;
}

// ---------------------------------------------------------------------------
// Output projection GEMM, 32x64 tiles, BK=64, double-buffered, counted
// vmcnt(3) with fused waitcnt+barrier asm. XCD-swizzled 512-block grid.
// ---------------------------------------------------------------------------
__global__ __launch_bounds__(256)
void gemm_proj(const u16* __restrict__ A, const u16* __restrict__ Bt,
               float* __restrict__ C)
{
    // u16 units: As0@0 As1@2048 Bs0@4096 Bs1@8192  (24KB total)
    __shared__ __align__(16) u16 S[12288];

    const int wg = (blockIdx.x & 7) * 64 + (blockIdx.x >> 3);
    const int n0 = (wg & 15) * 64;
    const int m0 = (wg >> 4) * 32;

    const int tid = threadIdx.x;
    const int l = tid & 63, w = tid >> 6;
    const int wr = (w & 1) * 16, wc = (w >> 1) * 32;
    const int srow = l >> 3;
    const int sslot = (l & 7) ^ srow;

    f32x4 acc[2];
    acc[0] = (f32x4){0.f, 0.f, 0.f, 0.f};
    acc[1] = (f32x4){0.f, 0.f, 0.f, 0.f};

    auto STAGE = [&](int buf, int k0) {
        const int rowa = w * 8 + srow;
        gload_lds16(A + (size_t)(m0 + rowa) * CDIM + k0 + sslot * 8,
                    &S[buf * 2048 + (w * 8) * 64]);
        #pragma unroll
        for (int q = 0; q < 2; ++q) {
            const int row = w * 16 + q * 8 + srow;
            gload_lds16(Bt + (size_t)(n0 + row) * CDIM + k0 + sslot * 8,
                        &S[4096 + buf * 4096 + (w * 16 + q * 8) * 64]);
        }
    };

    STAGE(0, 0);
    for (int t = 0; t < 16; ++t) {
        const int cur = t & 1;
        if (t < 15) {
            STAGE(cur ^ 1, (t + 1) * 64);
            PIPE_BAR_VM3();
        } else {
            PIPE_BAR_VM0();
        }

        const u16* Ab = &S[cur * 2048];
        const u16* Bb = &S[4096 + cur * 4096];
        #pragma unroll
        for (int kh = 0; kh < 2; ++kh) {
            const int ra = wr + (l & 15);
            const int sa = (kh * 4 + (l >> 4)) ^ (ra & 7);
            bf16x8 af = *(const bf16x8*)&Ab[ra * 64 + sa * 8];
            #pragma unroll
            for (int j = 0; j < 2; ++j) {
                const int rb = wc + j * 16 + (l & 15);
                const int sb = (kh * 4 + (l >> 4)) ^ (rb & 7);
                bf16x8 bfr = *(const bf16x8*)&Bb[rb * 64 + sb * 8];
                acc[j] = __builtin_amdgcn_mfma_f32_16x16x32_bf16(
                    af, bfr, acc[j], 0, 0, 0);
            }
        }
        PIPE_BAR_END();
    }

    #pragma unroll
    for (int j = 0; j < 2; ++j) {
        const int row = m0 + wr + (l >> 4) * 4;
        const int col = n0 + wc + j * 16 + (l & 15);
        #pragma unroll
        for (int r = 0; r < 4; ++r)
            C[(size_t)(row + r) * CDIM + col] = acc[j][r];
    }
}

// ---------------------------------------------------------------------------
extern "C" void kernel_launch(void* const* d_in, const int* in_sizes, int n_in,
                              void* d_out, int out_size, void* d_ws, size_t ws_size,
                              hipStream_t stream)
{
    (void)in_sizes; (void)n_in; (void)out_size; (void)ws_size;
    const float* x    = (const float*)d_in[0];
    const float* cosp = (const float*)d_in[1];
    const float* sinp = (const float*)d_in[2];
    const float* Wq   = (const float*)d_in[3];
    const float* Wk   = (const float*)d_in[4];
    const float* Wv   = (const float*)d_in[5];
    const float* Wo   = (const float*)d_in[6];
    const float* Wdq  = (const float*)d_in[7];
    const float* Wdk  = (const float*)d_in[8];
    float* out = (float*)d_out;

    const int M = BB * T_SEQ;                 // 1024
    const size_t MC = (size_t)M * CDIM;       // 1M elems
    char* p = (char*)d_ws;
    float* qdig = (float*)p; p += (size_t)M * NH * KD * 4;   // 512KB
    float* kdig = (float*)p; p += (size_t)M * NH * KD * 4;   // 512KB
    u16* xb   = (u16*)p; p += MC * 2;
    u16* wqt  = (u16*)p; p += MC * 2;
    u16* wkt  = (u16*)p; p += MC * 2;
    u16* wvt  = (u16*)p; p += MC * 2;
    u16* wot  = (u16*)p; p += MC * 2;
    u16* Vt   = (u16*)p; p += MC * 2;         // [b][h][d][t] bf16, 2MB
    u16* ybuf = (u16*)p; p += MC * 2;
    u16* pacc = (u16*)p; p += (size_t)1152 * 4096 * 2;       // 9.4MB bf16
    float* pdeng = (float*)p; p += (size_t)1152 * 64 * 4;

    dim3 blk(256);
    prep_kernel<<<dim3(32, 32, 5), blk, 0, stream>>>(
        x, Wq, Wk, Wv, Wo, xb, wqt, wkt, wvt, wot);
    gemm_qkv_fused<<<dim3(768), blk, 0, stream>>>(
        xb, wqt, wkt, wvt, cosp, sinp, Wdq, Wdk, qdig, kdig, Vt);
    attn_partial<<<dim3(1152), blk, 0, stream>>>(
        qdig, kdig, Vt, pacc, pdeng);
    attn_combine<<<dim3(16, NH, BB), blk, 0, stream>>>(pacc, pdeng, ybuf);
    gemm_proj<<<dim3(512), blk, 0, stream>>>(ybuf, wot, out);
}